// Round 6
// baseline (2051.572 us; speedup 1.0000x reference)
//
#include <hip/hip_runtime.h>
#include <hip/hip_bf16.h>

// Problem constants
#define B_SZ   16384
#define DIN    2048
#define H1_SZ  512
#define H2_SZ  128
#define N_EXP  8
#define N_CLS  10
#define N1     4608   // 8*512 experts + 512 gate
#define N2     1152   // 8*128 experts + 128 gate
#define NBLK   1024   // persistent blocks = 256 CU x 4 blocks/CU (124 regs, 32KB LDS)

typedef __attribute__((ext_vector_type(8))) __bf16 bf16x8;
typedef __attribute__((ext_vector_type(4))) float  floatx4;
typedef __attribute__((ext_vector_type(4))) short  short4v;
typedef __attribute__((ext_vector_type(8))) short  short8v;

__device__ __forceinline__ float bf2f(short s) {
  unsigned int u = ((unsigned int)(unsigned short)s) << 16;
  float f; __builtin_memcpy(&f, &u, 4); return f;
}

// Device-scope grid barrier (sense = one-shot flag per barrier, counters
// zeroed host-side each launch). tid0 release-fences (buffer_wbl2 sc1 ->
// XCD L2 writeback), arrives, waits, acquire-fences (buffer_inv). Requires
// all NBLK blocks co-resident: guaranteed by __launch_bounds__(256,4)
// (<=128 unified VGPRs) + 32KB LDS -> 4 blocks/CU x 256 CUs.
__device__ __forceinline__ void grid_barrier(unsigned* cnt, unsigned* flag) {
  __syncthreads();
  if (threadIdx.x == 0) {
    __threadfence();
    unsigned prev = __hip_atomic_fetch_add(cnt, 1u, __ATOMIC_ACQ_REL,
                                           __HIP_MEMORY_SCOPE_AGENT);
    if (prev == NBLK - 1) {
      __hip_atomic_store(flag, 1u, __ATOMIC_RELEASE, __HIP_MEMORY_SCOPE_AGENT);
    } else {
      while (__hip_atomic_load(flag, __ATOMIC_ACQUIRE,
                               __HIP_MEMORY_SCOPE_AGENT) == 0u)
        __builtin_amdgcn_s_sleep(2);
    }
    __threadfence();
  }
  __syncthreads();
}

// ---------------------------------------------------------------------------
// MFMA GEMM tile: C[128x128] = relu(A[128xK] @ BT^T + bias) -> bf16.
// R1-proven: XOR-swizzled LDS chunks (SQ_LDS_BANK_CONFLICT == 0 measured),
// global_load_lds width-16 staging, 2x2 waves of 4x4 16x16x32 MFMA tiles.
// Plain cached stores (R3: NT stores regressed).
// ---------------------------------------------------------------------------
__device__ __forceinline__ void gemm_tile(
    const __hip_bfloat16* A,  int lda,
    const __hip_bfloat16* BT, int K,
    const float* bias,
    __hip_bfloat16* O, int ldo,
    __hip_bfloat16* As, __hip_bfloat16* Bs) {
  const int tid  = threadIdx.x;
  const int lane = tid & 63;
  const int wave = tid >> 6;
  const int wm   = (wave >> 1) * 64;
  const int wn   = (wave & 1) * 64;
  const int lrow  = lane & 15;
  const int lquad = lane >> 4;

  floatx4 acc[4][4] = {};

  for (int k0 = 0; k0 < K; k0 += 64) {
    #pragma unroll
    for (int j = 0; j < 4; ++j) {
      int chunk = j * 256 + tid;       // 0..1023 chunks of 8 bf16 (16 B)
      int mi = chunk >> 3;             // tile row 0..127
      int cs = chunk & 7;              // stored chunk slot
      int cl = cs ^ (mi & 7);          // logical k-chunk in this slot
      __builtin_amdgcn_global_load_lds(
          (const __attribute__((address_space(1))) unsigned int*)(A + (size_t)mi * lda + k0 + cl * 8),
          (__attribute__((address_space(3))) unsigned int*)(As + chunk * 8),
          16, 0, 0);
      __builtin_amdgcn_global_load_lds(
          (const __attribute__((address_space(1))) unsigned int*)(BT + (size_t)mi * K + k0 + cl * 8),
          (__attribute__((address_space(3))) unsigned int*)(Bs + chunk * 8),
          16, 0, 0);
    }
    __syncthreads();
    #pragma unroll
    for (int ks = 0; ks < 2; ++ks) {
      bf16x8 a[4], b[4];
      #pragma unroll
      for (int t = 0; t < 4; ++t) {
        int ar = wm + t * 16 + lrow;
        int br = wn + t * 16 + lrow;
        int ca = (ks * 4 + lquad) ^ (ar & 7);
        int cb = (ks * 4 + lquad) ^ (br & 7);
        a[t] = *(const bf16x8*)(As + ar * 64 + ca * 8);
        b[t] = *(const bf16x8*)(Bs + br * 64 + cb * 8);
      }
      #pragma unroll
      for (int mt = 0; mt < 4; ++mt)
        #pragma unroll
        for (int nt = 0; nt < 4; ++nt)
          acc[mt][nt] = __builtin_amdgcn_mfma_f32_16x16x32_bf16(
              a[mt], b[nt], acc[mt][nt], 0, 0, 0);
    }
    __syncthreads();
  }

  // epilogue: bias + relu. C/D layout: col = lane&15, row = quad*4 + r.
  #pragma unroll
  for (int nt = 0; nt < 4; ++nt) {
    int col = wn + nt * 16 + lrow;
    float bv = bias[col];
    #pragma unroll
    for (int mt = 0; mt < 4; ++mt) {
      #pragma unroll
      for (int r = 0; r < 4; ++r) {
        int row = wm + mt * 16 + lquad * 4 + r;
        float v = acc[mt][nt][r] + bv;
        v = v > 0.f ? v : 0.f;
        O[(size_t)row * ldo + col] = __float2bfloat16(v);
      }
    }
  }
}

// ---------------------------------------------------------------------------
// Persistent mega-kernel: prep | gemm1 | gemm2 | layer3 with 3 grid barriers.
// ctr[0..5] = (cnt,flag) x3 barriers; ctr[6] = gemm1 steal; ctr[7] = gemm2
// steal. ctr lives in gate_out[0..15] (zeroed by 64B memset pre-launch;
// overwritten with real gate values by phase 4 AFTER the last barrier).
// ---------------------------------------------------------------------------
__global__ __launch_bounds__(256, 4) void mega_kernel(
    const float* __restrict__ fs, const float* __restrict__ fp,
    const float* __restrict__ gW1, const float* __restrict__ gb1,
    const float* __restrict__ gW2, const float* __restrict__ gb2,
    const float* __restrict__ gW3, const float* __restrict__ gb3,
    const float* __restrict__ eW1, const float* __restrict__ eb1,
    const float* __restrict__ eW2, const float* __restrict__ eb2,
    const float* __restrict__ eW3, const float* __restrict__ eb3,
    __hip_bfloat16* X,            // aliased by H2 after phase 2
    __hip_bfloat16* W1T, __hip_bfloat16* W2T,
    __hip_bfloat16* H1,  __hip_bfloat16* H2,
    float* out, float* gate_out, unsigned* ctr) {
  __shared__ __align__(16) __hip_bfloat16 smem[2 * 128 * 64];  // 32 KB
  __hip_bfloat16* As = smem;
  __hip_bfloat16* Bs = smem + 128 * 64;
  __shared__ int s_t;

  const int pid = blockIdx.x;
  const int tid = threadIdx.x;

  // ================= phase 1a: features concat -> bf16 X ===================
  {
    const int nf4 = B_SZ * (DIN / 4);          // 8,388,608 float4 chunks
    const float4* fs4 = (const float4*)fs;
    const float4* fp4 = (const float4*)fp;
    for (int i = pid * 256 + tid; i < nf4; i += NBLK * 256) {
      int c = i & 511;
      int row = i >> 9;
      float4 v = (c < 256) ? fs4[(size_t)row * 256 + c]
                           : fp4[(size_t)row * 256 + (c - 256)];
      union { short4v v4; __hip_bfloat16 h[4]; } u;
      u.h[0] = __float2bfloat16(v.x);
      u.h[1] = __float2bfloat16(v.y);
      u.h[2] = __float2bfloat16(v.z);
      u.h[3] = __float2bfloat16(v.w);
      *(short4v*)(X + (size_t)i * 4) = u.v4;
    }
  }
  // ================= phase 1b: weight transpose-convert ====================
  {
    float (*tbuf)[33] = (float(*)[33])smem;    // 4.2 KB, aliases As
    const int NT1 = 64 * 144;                  // W1: 9216 32x32 tiles
    const int NT2 = 16 * 36;                   // W2: 576 tiles
    int tx = tid & 31, ty = tid >> 5;
    for (int t = pid; t < NT1 + NT2; t += NBLK) {
      const float* esrc; const float* gsrc; __hip_bfloat16* o;
      int K, H, bx, by;
      if (t < NT1) { bx = t & 63; by = t >> 6; esrc = eW1; gsrc = gW1; o = W1T; K = DIN;   H = H1_SZ; }
      else { int q = t - NT1; bx = q & 15; by = q >> 4; esrc = eW2; gsrc = gW2; o = W2T; K = H1_SZ; H = H2_SZ; }
      int k0 = bx * 32, n0 = by * 32;
      int e = n0 / H;
      const float* src; int h0;
      if (e < N_EXP) { src = esrc + (size_t)e * K * H; h0 = n0 - e * H; }
      else           { src = gsrc;                     h0 = n0 - N_EXP * H; }
      __syncthreads();   // protect smem reuse across loop iterations
      #pragma unroll
      for (int j = 0; j < 4; ++j) {
        int r = ty + j * 8;
        tbuf[r][tx] = src[(size_t)(k0 + r) * H + h0 + tx];
      }
      __syncthreads();
      #pragma unroll
      for (int j = 0; j < 4; ++j) {
        int r = ty + j * 8;
        o[(size_t)(n0 + r) * K + k0 + tx] = __float2bfloat16(tbuf[tx][r]);
      }
    }
  }

  grid_barrier(ctr + 0, ctr + 1);

  // ================= phase 2: gemm1 (work-stolen, n-major order) ===========
  // R2-proven ordering: tile id n-fast (R4's m-major flip regressed).
  for (;;) {
    __syncthreads();
    if (tid == 0)
      s_t = (int)__hip_atomic_fetch_add(&ctr[6], 1u, __ATOMIC_RELAXED,
                                        __HIP_MEMORY_SCOPE_AGENT);
    __syncthreads();
    int t = s_t;
    if (t >= 36 * 128) break;
    int nt = t % 36, mt = t / 36;
    int n0 = nt * 128, m0 = mt * 128;
    const float* bias = (n0 < N_EXP * H1_SZ) ? (eb1 + n0) : (gb1 + (n0 - N_EXP * H1_SZ));
    gemm_tile(X + (size_t)m0 * DIN, DIN,
              W1T + (size_t)n0 * DIN, DIN,
              bias,
              H1 + (size_t)m0 * N1 + n0, N1, As, Bs);
  }

  grid_barrier(ctr + 2, ctr + 3);

  // ================= phase 3: gemm2 (work-stolen) ==========================
  for (;;) {
    __syncthreads();
    if (tid == 0)
      s_t = (int)__hip_atomic_fetch_add(&ctr[7], 1u, __ATOMIC_RELAXED,
                                        __HIP_MEMORY_SCOPE_AGENT);
    __syncthreads();
    int t = s_t;
    if (t >= 128 * (N_EXP + 1)) break;
    int mt = t & 127, z = t >> 7;
    int m0 = mt * 128;
    const float* bias = (z < N_EXP) ? (eb2 + z * H2_SZ) : gb2;
    gemm_tile(H1 + (size_t)m0 * N1 + z * H1_SZ, N1,
              W2T + (size_t)z * H2_SZ * H1_SZ, H1_SZ,
              bias,
              H2 + (size_t)m0 * N2 + z * H2_SZ, N2, As, Bs);
  }

  grid_barrier(ctr + 4, ctr + 5);

  // ================= phase 4: layer 3 (static, 512 groups of 32 rows) ======
  for (int g = pid; g < B_SZ / 32; g += NBLK) {
    int j    = tid & 7;
    int rloc = tid >> 3;
    long row = (long)g * 32 + rloc;
    const __hip_bfloat16* hrow = H2 + row * N2;

    float accg = 0.f;
    float acc[N_CLS];
    #pragma unroll
    for (int c = 0; c < N_CLS; ++c) acc[c] = 0.f;

    #pragma unroll 4
    for (int k8 = 0; k8 < 16; ++k8) {
      short8v hg8 = *(const short8v*)(hrow + N_EXP * H2_SZ + k8 * 8);
      short8v he8 = *(const short8v*)(hrow + j * H2_SZ + k8 * 8);
      #pragma unroll
      for (int t = 0; t < 8; ++t) {
        int k = k8 * 8 + t;
        float hg = bf2f(hg8[t]);
        float he = bf2f(he8[t]);
        accg += hg * gW3[k * N_EXP + j];
        const float* w = eW3 + (size_t)(j * H2_SZ + k) * N_CLS;
        #pragma unroll
        for (int c = 0; c < N_CLS; ++c) acc[c] += he * w[c];
      }
    }

    float gj = accg + gb3[j];
    float mx = gj;
    mx = fmaxf(mx, __shfl_xor(mx, 1));
    mx = fmaxf(mx, __shfl_xor(mx, 2));
    mx = fmaxf(mx, __shfl_xor(mx, 4));
    float ex = __expf(gj - mx);
    float s = ex;
    s += __shfl_xor(s, 1);
    s += __shfl_xor(s, 2);
    s += __shfl_xor(s, 4);
    float gp = ex / s;

    float lg[N_CLS];
    float lm = -1e30f;
    #pragma unroll
    for (int c = 0; c < N_CLS; ++c) {
      lg[c] = acc[c] + eb3[j * N_CLS + c];
      lm = fmaxf(lm, lg[c]);
    }
    float es = 0.f;
    #pragma unroll
    for (int c = 0; c < N_CLS; ++c) es += __expf(lg[c] - lm);
    float lse = lm + __logf(es);

    float o[N_CLS];
    #pragma unroll
    for (int c = 0; c < N_CLS; ++c) o[c] = gp * (lg[c] - lse);
    #pragma unroll
    for (int c = 0; c < N_CLS; ++c) {
      o[c] += __shfl_xor(o[c], 1);
      o[c] += __shfl_xor(o[c], 2);
      o[c] += __shfl_xor(o[c], 4);
    }

    gate_out[row * N_EXP + j] = gp;
    if (j == 0) {
      #pragma unroll
      for (int c = 0; c < N_CLS; ++c) out[row * N_CLS + c] = o[c];
    }
  }
}

// ---------------------------------------------------------------------------
extern "C" void kernel_launch(void* const* d_in, const int* in_sizes, int n_in,
                              void* d_out, int out_size, void* d_ws, size_t ws_size,
                              hipStream_t stream) {
  const float* fs  = (const float*)d_in[0];
  const float* fp  = (const float*)d_in[1];
  const float* gW1 = (const float*)d_in[2];
  const float* gb1 = (const float*)d_in[3];
  const float* gW2 = (const float*)d_in[4];
  const float* gb2 = (const float*)d_in[5];
  const float* gW3 = (const float*)d_in[6];
  const float* gb3 = (const float*)d_in[7];
  const float* eW1 = (const float*)d_in[8];
  const float* eb1 = (const float*)d_in[9];
  const float* eW2 = (const float*)d_in[10];
  const float* eb2 = (const float*)d_in[11];
  const float* eW3 = (const float*)d_in[12];
  const float* eb3 = (const float*)d_in[13];
  float* out = (float*)d_out;                   // [B,10] then [B,8]
  float* gate_out = out + (size_t)B_SZ * N_CLS;

  // workspace layout (bytes):
  //   X   : 0          .. 67,108,864   (B*2048 bf16)  -- aliased by H2 later
  //   W1T : 67,108,864 .. 85,983,232   (4608*2048 bf16)
  //   W2T : 85,983,232 .. 87,162,880   (1152*512 bf16)
  //   H1  : 87,162,880 .. 238,157,824  (B*4608 bf16)
  char* ws = (char*)d_ws;
  __hip_bfloat16* X   = (__hip_bfloat16*)ws;
  __hip_bfloat16* H2  = X;   // alias: X dead after phase 2 (barrier-separated)
  __hip_bfloat16* W1T = (__hip_bfloat16*)(ws + 67108864);
  __hip_bfloat16* W2T = (__hip_bfloat16*)(ws + 85983232);
  __hip_bfloat16* H1  = (__hip_bfloat16*)(ws + 87162880);

  // barrier/steal counters: first 16 floats of gate_out (rewritten by phase 4
  // after the final barrier). Zeroed every call -> same work every call.
  unsigned* ctr = (unsigned*)gate_out;
  hipMemsetAsync(ctr, 0, 64, stream);

  mega_kernel<<<NBLK, 256, 0, stream>>>(
      fs, fp, gW1, gb1, gW2, gb2, gW3, gb3,
      eW1, eb1, eW2, eb2, eW3, eb3,
      X, W1T, W2T, H1, H2, out, gate_out, ctr);
}

// Round 7
// 743.805 us; speedup vs baseline: 2.7582x; 2.7582x over previous
//
#include <hip/hip_runtime.h>
#include <hip/hip_bf16.h>

// Problem constants
#define B_SZ   16384
#define DIN    2048
#define H1_SZ  512
#define H2_SZ  128
#define N_EXP  8
#define N_CLS  10
#define N1     4608   // 8*512 experts + 512 gate
#define N2     1152   // 8*128 experts + 128 gate

typedef __attribute__((ext_vector_type(8))) __bf16 bf16x8;
typedef __attribute__((ext_vector_type(4))) float  floatx4;
typedef __attribute__((ext_vector_type(4))) short  short4v;
typedef __attribute__((ext_vector_type(8))) short  short8v;

__device__ __forceinline__ float bf2f(short s) {
  unsigned int u = ((unsigned int)(unsigned short)s) << 16;
  float f; __builtin_memcpy(&f, &u, 4); return f;
}

// ---------------------------------------------------------------------------
// Merged prep kernel (R4-proven):
//   blocks [0,2048)      : features = concat(fs,fp) -> bf16 X[B][DIN]
//   blocks [2048,11264)  : transpose-convert W1 -> W1T (4608 x 2048)
//   blocks [11264,11840) : transpose-convert W2 -> W2T (1152 x 512)
// ---------------------------------------------------------------------------
__global__ __launch_bounds__(256) void prep_kernel(
    const float* __restrict__ fs, const float* __restrict__ fp,
    const float* __restrict__ eW1, const float* __restrict__ gW1,
    const float* __restrict__ eW2, const float* __restrict__ gW2,
    __hip_bfloat16* __restrict__ X,
    __hip_bfloat16* __restrict__ W1T,
    __hip_bfloat16* __restrict__ W2T) {
  __shared__ float tbuf[32][33];
  const int b   = blockIdx.x;
  const int tid = threadIdx.x;

  if (b < 2048) {
    const int nf4 = B_SZ * (DIN / 4);          // 8,388,608 float4 chunks
    const float4* fs4 = (const float4*)fs;
    const float4* fp4 = (const float4*)fp;
    for (int i = b * 256 + tid; i < nf4; i += 2048 * 256) {
      int c = i & 511;
      int row = i >> 9;
      float4 v = (c < 256) ? fs4[(size_t)row * 256 + c]
                           : fp4[(size_t)row * 256 + (c - 256)];
      union { short4v v4; __hip_bfloat16 h[4]; } u;
      u.h[0] = __float2bfloat16(v.x);
      u.h[1] = __float2bfloat16(v.y);
      u.h[2] = __float2bfloat16(v.z);
      u.h[3] = __float2bfloat16(v.w);
      *(short4v*)(X + (size_t)i * 4) = u.v4;
    }
  } else {
    const float* esrc; const float* gsrc; __hip_bfloat16* out;
    int K, H, bx, by;
    if (b < 2048 + 9216) {
      int t = b - 2048;  bx = t & 63; by = t >> 6;   // 64 x 144 tiles
      esrc = eW1; gsrc = gW1; out = W1T; K = DIN; H = H1_SZ;
    } else {
      int t = b - 11264; bx = t & 15; by = t >> 4;   // 16 x 36 tiles
      esrc = eW2; gsrc = gW2; out = W2T; K = H1_SZ; H = H2_SZ;
    }
    int k0 = bx * 32, n0 = by * 32;   // 32 | H, tile never straddles experts
    int e = n0 / H;
    const float* src; int h0;
    if (e < N_EXP) { src = esrc + (size_t)e * K * H; h0 = n0 - e * H; }
    else           { src = gsrc;                     h0 = n0 - N_EXP * H; }
    int tx = tid & 31, ty = tid >> 5;
    #pragma unroll
    for (int j = 0; j < 4; ++j) {
      int r = ty + j * 8;
      tbuf[r][tx] = src[(size_t)(k0 + r) * H + h0 + tx];
    }
    __syncthreads();
    #pragma unroll
    for (int j = 0; j < 4; ++j) {
      int r = ty + j * 8;
      out[(size_t)(n0 + r) * K + k0 + tx] = __float2bfloat16(tbuf[tx][r]);
    }
  }
}

// ---------------------------------------------------------------------------
// gemm1: C[128x128] = relu(X[128xK] @ W1T^T + b1) -> H1. R2-proven config:
// XOR-swizzled LDS (SQ_LDS_BANK_CONFLICT == 0), width-16 global_load_lds,
// n-major grid (dim3(36,128)) -- R4's m-major flip regressed, reverted.
// Plain cached stores (R3: NT stores regressed).
// ---------------------------------------------------------------------------
__global__ __launch_bounds__(256, 4) void gemm1_kernel(
    const __hip_bfloat16* __restrict__ X, const __hip_bfloat16* __restrict__ W1T,
    const float* __restrict__ eb1, const float* __restrict__ gb1,
    __hip_bfloat16* __restrict__ H1) {
  __shared__ __align__(16) __hip_bfloat16 As[128 * 64];
  __shared__ __align__(16) __hip_bfloat16 Bs[128 * 64];

  const int tid  = threadIdx.x;
  const int lane = tid & 63;
  const int wave = tid >> 6;
  const int wm   = (wave >> 1) * 64;
  const int wn   = (wave & 1) * 64;
  const int lrow  = lane & 15;
  const int lquad = lane >> 4;

  const int m0 = blockIdx.y * 128;
  const int n0 = blockIdx.x * 128;
  const float* bias = (n0 < N_EXP * H1_SZ) ? (eb1 + n0) : (gb1 + (n0 - N_EXP * H1_SZ));
  const __hip_bfloat16* A  = X   + (size_t)m0 * DIN;
  const __hip_bfloat16* BT = W1T + (size_t)n0 * DIN;
  __hip_bfloat16* O = H1 + (size_t)m0 * N1 + n0;

  floatx4 acc[4][4] = {};

  for (int k0 = 0; k0 < DIN; k0 += 64) {
    #pragma unroll
    for (int j = 0; j < 4; ++j) {
      int chunk = j * 256 + tid;       // 16B chunks
      int mi = chunk >> 3;
      int cs = chunk & 7;
      int cl = cs ^ (mi & 7);          // XOR swizzle
      __builtin_amdgcn_global_load_lds(
          (const __attribute__((address_space(1))) unsigned int*)(A + (size_t)mi * DIN + k0 + cl * 8),
          (__attribute__((address_space(3))) unsigned int*)(As + chunk * 8),
          16, 0, 0);
      __builtin_amdgcn_global_load_lds(
          (const __attribute__((address_space(1))) unsigned int*)(BT + (size_t)mi * DIN + k0 + cl * 8),
          (__attribute__((address_space(3))) unsigned int*)(Bs + chunk * 8),
          16, 0, 0);
    }
    __syncthreads();
    #pragma unroll
    for (int ks = 0; ks < 2; ++ks) {
      bf16x8 a[4], b[4];
      #pragma unroll
      for (int t = 0; t < 4; ++t) {
        int ar = wm + t * 16 + lrow;
        int br = wn + t * 16 + lrow;
        int ca = (ks * 4 + lquad) ^ (ar & 7);
        int cb = (ks * 4 + lquad) ^ (br & 7);
        a[t] = *(const bf16x8*)(As + ar * 64 + ca * 8);
        b[t] = *(const bf16x8*)(Bs + br * 64 + cb * 8);
      }
      #pragma unroll
      for (int mt = 0; mt < 4; ++mt)
        #pragma unroll
        for (int nt = 0; nt < 4; ++nt)
          acc[mt][nt] = __builtin_amdgcn_mfma_f32_16x16x32_bf16(
              a[mt], b[nt], acc[mt][nt], 0, 0, 0);
    }
    __syncthreads();
  }

  #pragma unroll
  for (int nt = 0; nt < 4; ++nt) {
    int col = wn + nt * 16 + lrow;
    float bv = bias[col];
    #pragma unroll
    for (int mt = 0; mt < 4; ++mt) {
      #pragma unroll
      for (int r = 0; r < 4; ++r) {
        int row = wm + mt * 16 + lquad * 4 + r;
        float v = acc[mt][nt][r] + bv;
        v = v > 0.f ? v : 0.f;
        O[(size_t)row * N1 + col] = __float2bfloat16(v);
      }
    }
  }
}

// ---------------------------------------------------------------------------
// Fused gemm2 + layer3. Block = 64 batch rows. For z in 0..8: compute the
// 64x128 H2 z-slice = relu(H1_slice @ W2T[z]^T + b2) into LDS (never HBM),
// then GEMV it against W3 into a per-row logits buffer (8 gate + 80 expert
// floats/row). After the z-loop: gate softmax + expert log_softmax + weighted
// sum -> out. Saves the 38 MB H2 write + 38 MB read + one dispatch.
// LDS: As 8K + Bs 16K + H2L 16.25K + logitsL 22.5K = 63 KB -> 2 blocks/CU.
// ---------------------------------------------------------------------------
__global__ __launch_bounds__(256, 2) void fused23_kernel(
    const __hip_bfloat16* __restrict__ H1, const __hip_bfloat16* __restrict__ W2T,
    const float* __restrict__ eb2, const float* __restrict__ gb2,
    const float* __restrict__ gW3, const float* __restrict__ gb3,
    const float* __restrict__ eW3, const float* __restrict__ eb3,
    float* __restrict__ out, float* __restrict__ gate_out) {
  __shared__ __align__(16) __hip_bfloat16 As[64 * 64];     //  8 KB
  __shared__ __align__(16) __hip_bfloat16 Bs[128 * 64];    // 16 KB
  __shared__ __align__(16) __hip_bfloat16 H2L[64 * 130];   // 16.25 KB (pad 130)
  __shared__ float logitsL[64][90];                        // 22.5 KB: [0..7]=gate, [8+j*10+c]=expert j class c

  const int tid  = threadIdx.x;
  const int lane = tid & 63;
  const int wave = tid >> 6;
  const int wm2  = (wave >> 1) * 32;    // 0 or 32
  const int wn2  = (wave & 1) * 64;     // 0 or 64
  const int lrow  = lane & 15;
  const int lquad = lane >> 4;
  const int m0 = blockIdx.x * 64;

  const int grow = tid >> 2;            // GEMV: 4 threads per row
  const int gpart = tid & 3;

  for (int z = 0; z < N_EXP + 1; ++z) {
    const __hip_bfloat16* A  = H1  + (size_t)m0 * N1 + z * H1_SZ;
    const __hip_bfloat16* BT = W2T + (size_t)z * H2_SZ * H1_SZ;
    const float* bias2 = (z < N_EXP) ? (eb2 + z * H2_SZ) : gb2;

    floatx4 acc[2][4] = {};
    for (int k0 = 0; k0 < H1_SZ; k0 += 64) {
      // stage A: 512 chunks (2/thread)
      #pragma unroll
      for (int j = 0; j < 2; ++j) {
        int chunk = j * 256 + tid;
        int mi = chunk >> 3, cs = chunk & 7, cl = cs ^ (mi & 7);
        __builtin_amdgcn_global_load_lds(
            (const __attribute__((address_space(1))) unsigned int*)(A + (size_t)mi * N1 + k0 + cl * 8),
            (__attribute__((address_space(3))) unsigned int*)(As + chunk * 8),
            16, 0, 0);
      }
      // stage B: 1024 chunks (4/thread)
      #pragma unroll
      for (int j = 0; j < 4; ++j) {
        int idx = j * 256 + tid;
        int row = idx >> 3, cs = idx & 7, cl = cs ^ (row & 7);
        __builtin_amdgcn_global_load_lds(
            (const __attribute__((address_space(1))) unsigned int*)(BT + (size_t)row * H1_SZ + k0 + cl * 8),
            (__attribute__((address_space(3))) unsigned int*)(Bs + idx * 8),
            16, 0, 0);
      }
      __syncthreads();
      #pragma unroll
      for (int ks = 0; ks < 2; ++ks) {
        bf16x8 a[2], b[4];
        #pragma unroll
        for (int t = 0; t < 2; ++t) {
          int ar = wm2 + t * 16 + lrow;
          int ca = (ks * 4 + lquad) ^ (ar & 7);
          a[t] = *(const bf16x8*)(As + ar * 64 + ca * 8);
        }
        #pragma unroll
        for (int t = 0; t < 4; ++t) {
          int br = wn2 + t * 16 + lrow;
          int cb = (ks * 4 + lquad) ^ (br & 7);
          b[t] = *(const bf16x8*)(Bs + br * 64 + cb * 8);
        }
        #pragma unroll
        for (int mt = 0; mt < 2; ++mt)
          #pragma unroll
          for (int nt = 0; nt < 4; ++nt)
            acc[mt][nt] = __builtin_amdgcn_mfma_f32_16x16x32_bf16(
                a[mt], b[nt], acc[mt][nt], 0, 0, 0);
      }
      __syncthreads();   // also guards H2L: prior GEMV reads done before epilogue writes
    }

    // epilogue: bias+relu -> H2L (LDS). pad-130 rows: 65 dwords, odd -> no conflicts.
    #pragma unroll
    for (int nt = 0; nt < 4; ++nt) {
      int col = wn2 + nt * 16 + lrow;
      float bv = bias2[col];
      #pragma unroll
      for (int mt = 0; mt < 2; ++mt) {
        #pragma unroll
        for (int r = 0; r < 4; ++r) {
          int row = wm2 + mt * 16 + lquad * 4 + r;
          float v = acc[mt][nt][r] + bv;
          v = v > 0.f ? v : 0.f;
          H2L[row * 130 + col] = __float2bfloat16(v);
        }
      }
    }
    __syncthreads();

    // GEMV: logits for this z. 4 threads/row; same-row threads broadcast H2L.
    if (z < N_EXP) {
      float accv[3] = {0.f, 0.f, 0.f};
      const float* w = eW3 + (size_t)z * H2_SZ * N_CLS;
      for (int k = 0; k < H2_SZ; ++k) {
        float h = bf2f(*(const short*)(H2L + grow * 130 + k));
        #pragma unroll
        for (int i = 0; i < 3; ++i) {
          int c = gpart + 4 * i;
          if (c < N_CLS) accv[i] += h * w[k * N_CLS + c];
        }
      }
      #pragma unroll
      for (int i = 0; i < 3; ++i) {
        int c = gpart + 4 * i;
        if (c < N_CLS)
          logitsL[grow][8 + z * 10 + c] = accv[i] + eb3[z * N_CLS + c];
      }
    } else {
      float accv[2] = {0.f, 0.f};
      for (int k = 0; k < H2_SZ; ++k) {
        float h = bf2f(*(const short*)(H2L + grow * 130 + k));
        #pragma unroll
        for (int i = 0; i < 2; ++i)
          accv[i] += h * gW3[k * N_EXP + gpart + 4 * i];
      }
      #pragma unroll
      for (int i = 0; i < 2; ++i)
        logitsL[grow][gpart + 4 * i] = accv[i] + gb3[gpart + 4 * i];
    }
  }
  __syncthreads();

  // final epilogue: 1 thread per row (threads 0..63)
  if (tid < 64) {
    const float* L = logitsL[tid];
    long row = m0 + tid;
    // gate softmax
    float mx = L[0];
    #pragma unroll
    for (int j = 1; j < 8; ++j) mx = fmaxf(mx, L[j]);
    float gs = 0.f, gp[8];
    #pragma unroll
    for (int j = 0; j < 8; ++j) { gp[j] = __expf(L[j] - mx); gs += gp[j]; }
    float inv = 1.f / gs;
    #pragma unroll
    for (int j = 0; j < 8; ++j) gp[j] *= inv;

    float ov[N_CLS];
    #pragma unroll
    for (int c = 0; c < N_CLS; ++c) ov[c] = 0.f;
    #pragma unroll
    for (int j = 0; j < 8; ++j) {
      const float* lg = L + 8 + j * 10;
      float lm = lg[0];
      #pragma unroll
      for (int c = 1; c < N_CLS; ++c) lm = fmaxf(lm, lg[c]);
      float es = 0.f;
      #pragma unroll
      for (int c = 0; c < N_CLS; ++c) es += __expf(lg[c] - lm);
      float lse = lm + __logf(es);
      #pragma unroll
      for (int c = 0; c < N_CLS; ++c) ov[c] += gp[j] * (lg[c] - lse);
    }
    #pragma unroll
    for (int c = 0; c < N_CLS; ++c) out[row * N_CLS + c] = ov[c];
    #pragma unroll
    for (int j = 0; j < 8; ++j) gate_out[row * N_EXP + j] = gp[j];
  }
}

// ---------------------------------------------------------------------------
extern "C" void kernel_launch(void* const* d_in, const int* in_sizes, int n_in,
                              void* d_out, int out_size, void* d_ws, size_t ws_size,
                              hipStream_t stream) {
  const float* fs  = (const float*)d_in[0];
  const float* fp  = (const float*)d_in[1];
  const float* gW1 = (const float*)d_in[2];
  const float* gb1 = (const float*)d_in[3];
  const float* gW2 = (const float*)d_in[4];
  const float* gb2 = (const float*)d_in[5];
  const float* gW3 = (const float*)d_in[6];
  const float* gb3 = (const float*)d_in[7];
  const float* eW1 = (const float*)d_in[8];
  const float* eb1 = (const float*)d_in[9];
  const float* eW2 = (const float*)d_in[10];
  const float* eb2 = (const float*)d_in[11];
  const float* eW3 = (const float*)d_in[12];
  const float* eb3 = (const float*)d_in[13];
  float* out = (float*)d_out;                   // [B,10] then [B,8]
  float* gate_out = out + (size_t)B_SZ * N_CLS;

  // workspace layout (bytes):
  //   X   : 0          .. 67,108,864   (B*2048 bf16)
  //   W1T : 67,108,864 .. 85,983,232   (4608*2048 bf16)
  //   W2T : 85,983,232 .. 87,162,880   (1152*512 bf16)
  //   H1  : 87,162,880 .. 238,157,824  (B*4608 bf16)
  char* ws = (char*)d_ws;
  __hip_bfloat16* X   = (__hip_bfloat16*)ws;
  __hip_bfloat16* W1T = (__hip_bfloat16*)(ws + 67108864);
  __hip_bfloat16* W2T = (__hip_bfloat16*)(ws + 85983232);
  __hip_bfloat16* H1  = (__hip_bfloat16*)(ws + 87162880);

  prep_kernel<<<11840, 256, 0, stream>>>(fs, fp, eW1, gW1, eW2, gW2, X, W1T, W2T);
  gemm1_kernel<<<dim3(N1 / 128, B_SZ / 128), 256, 0, stream>>>(X, W1T, eb1, gb1, H1);
  fused23_kernel<<<B_SZ / 64, 256, 0, stream>>>(H1, W2T, eb2, gb2,
                                                gW3, gb3, eW3, eb3,
                                                out, gate_out);
}